// Round 1
// baseline (4668.350 us; speedup 1.0000x reference)
//
#include <hip/hip_runtime.h>

typedef __bf16 bf16_t;
typedef bf16_t bf16x8 __attribute__((ext_vector_type(8)));
typedef float  f32x4  __attribute__((ext_vector_type(4)));

#define TT 512
#define BB 1024

// packed weight chunk bases (16B chunks). Layer k: [N,K] row-major source.
#define cL0   0      // enc1_s  N=128 K=64   (folded We1a*Wphi_s)
#define cL1   1024   // enc1_h  N=128 K=128  (We1[:,128:])
#define cL2   3072   // enc2    N=128 K=128
#define cL3   5120   // pri1    N=128 K=128
#define cL4   7168   // pri2    N=128 K=128
#define cL5   9216   // dec1_z  N=128 K=64   (folded Wd1a*Wphi_z)
#define cL6   10240  // dec1_h  N=128 K=128  (Wd1[:,128:])
#define cL7   12288  // dec2    N=64  K=128
#define cL8   13312  // gates_s N=512 K=64   (folded Wih_a*Wphi_s)
#define cL9   17408  // gates_z N=512 K=64   (folded Wih_b*Wphi_z)
#define cL10  21504  // gates_h N=512 K=128  (W_hh)
#define NCHUNK 29696

#define WS_FBIAS_OFF 475136   // bytes: 768 floats (b_enc1[128], b_dec1[128], b_g[512])
#define WS_FOLD_OFF  478208   // bytes: 81920 floats (A_es, A_ds, G_s, G_z)

__device__ __forceinline__ f32x4 mfma16(bf16x8 a, bf16x8 b, f32x4 c) {
  return __builtin_amdgcn_mfma_f32_16x16x32_bf16(a, b, c, 0, 0, 0);
}
__device__ __forceinline__ float sigm(float x) { return 1.0f / (1.0f + __expf(-x)); }
__device__ __forceinline__ float tanh_f(float x) {
  x = fminf(fmaxf(x, -15.0f), 15.0f);
  float e = __expf(2.0f * x);
  return (e - 1.0f) / (e + 1.0f);
}
__device__ __forceinline__ float softplus_f(float x) {
  return (x > 15.0f) ? x : __logf(1.0f + __expf(x));
}

// ---------------- setup kernel 1: fold phi layers into downstream weights ----------------
__global__ void vrnn_fold(const float* __restrict__ We1, const float* __restrict__ Wd1,
                          const float* __restrict__ Wih,
                          const float* __restrict__ Wps, const float* __restrict__ Wpz,
                          const float* __restrict__ bps, const float* __restrict__ bpz,
                          const float* __restrict__ be1, const float* __restrict__ bd1,
                          const float* __restrict__ bih, const float* __restrict__ bhh,
                          float* __restrict__ fold, float* __restrict__ fbias) {
  int id = blockIdx.x * 256 + threadIdx.x;
  if (id < 8192) {                                  // A_es = We1[:, :128] @ Wphi_s  [128,64]
    int n = id >> 6, k = id & 63; float acc = 0.f;
    for (int j = 0; j < 128; ++j) acc += We1[n*256 + j] * Wps[j*64 + k];
    fold[id] = acc;
  } else if (id < 16384) {                          // A_ds = Wd1[:, :128] @ Wphi_z  [128,64]
    int q = id - 8192; int n = q >> 6, k = q & 63; float acc = 0.f;
    for (int j = 0; j < 128; ++j) acc += Wd1[n*256 + j] * Wpz[j*64 + k];
    fold[id] = acc;
  } else if (id < 49152) {                          // G_s = Wih[:, :128] @ Wphi_s  [512,64]
    int q = id - 16384; int n = q >> 6, k = q & 63; float acc = 0.f;
    for (int j = 0; j < 128; ++j) acc += Wih[n*256 + j] * Wps[j*64 + k];
    fold[id] = acc;
  } else if (id < 81920) {                          // G_z = Wih[:, 128:] @ Wphi_z  [512,64]
    int q = id - 49152; int n = q >> 6, k = q & 63; float acc = 0.f;
    for (int j = 0; j < 128; ++j) acc += Wih[n*256 + 128 + j] * Wpz[j*64 + k];
    fold[id] = acc;
  } else if (id < 82048) {                          // b_enc1 = be1 + We1a@b_phi_s
    int n = id - 81920; float acc = be1[n];
    for (int j = 0; j < 128; ++j) acc += We1[n*256 + j] * bps[j];
    fbias[n] = acc;
  } else if (id < 82176) {                          // b_dec1 = bd1 + Wd1a@b_phi_z
    int n = id - 82048; float acc = bd1[n];
    for (int j = 0; j < 128; ++j) acc += Wd1[n*256 + j] * bpz[j];
    fbias[128 + n] = acc;
  } else if (id < 82688) {                          // b_g = bih + bhh + Wih_a@bps + Wih_b@bpz
    int n = id - 82176; float acc = bih[n] + bhh[n];
    for (int j = 0; j < 128; ++j) acc += Wih[n*256 + j]*bps[j] + Wih[n*256 + 128 + j]*bpz[j];
    fbias[256 + n] = acc;
  }
}

// ---------------- setup kernel 2: pack all layers into MFMA B-fragment order (bf16) --------
// chunk c (16B) = layer base + (nt*Kt + kt)*64 + lane; lane holds W[n][k..k+7],
// n = nt*16 + (lane&15), k = kt*32 + (lane>>4)*8.
__global__ void vrnn_pack(const float* __restrict__ fold,
                          const float* __restrict__ We1, const float* __restrict__ We2,
                          const float* __restrict__ Wp1, const float* __restrict__ Wp2,
                          const float* __restrict__ Wd1, const float* __restrict__ Wd2,
                          const float* __restrict__ Whh,
                          bf16_t* __restrict__ packed) {
  int c = blockIdx.x * 256 + threadIdx.x;
  if (c >= NCHUNK) return;
  const float* src; int rs, co, Kt, base;
  if      (c < 1024)  { base = cL0;  src = fold;          rs = 64;  co = 0;   Kt = 2; }
  else if (c < 3072)  { base = cL1;  src = We1;           rs = 256; co = 128; Kt = 4; }
  else if (c < 5120)  { base = cL2;  src = We2;           rs = 128; co = 0;   Kt = 4; }
  else if (c < 7168)  { base = cL3;  src = Wp1;           rs = 128; co = 0;   Kt = 4; }
  else if (c < 9216)  { base = cL4;  src = Wp2;           rs = 128; co = 0;   Kt = 4; }
  else if (c < 10240) { base = cL5;  src = fold + 8192;   rs = 64;  co = 0;   Kt = 2; }
  else if (c < 12288) { base = cL6;  src = Wd1;           rs = 256; co = 128; Kt = 4; }
  else if (c < 13312) { base = cL7;  src = Wd2;           rs = 128; co = 0;   Kt = 4; }
  else if (c < 17408) { base = cL8;  src = fold + 16384;  rs = 64;  co = 0;   Kt = 2; }
  else if (c < 21504) { base = cL9;  src = fold + 49152;  rs = 64;  co = 0;   Kt = 2; }
  else                { base = cL10; src = Whh;           rs = 128; co = 0;   Kt = 4; }
  int local = c - base;
  int nt = local / (Kt * 64);
  int r = local - nt * Kt * 64;
  int kt = r >> 6, lane = r & 63;
  int n = nt * 16 + (lane & 15);
  int k = kt * 32 + (lane >> 4) * 8;
  const float* p = src + n * rs + co + k;
  bf16x8 v;
  #pragma unroll
  for (int j = 0; j < 8; ++j) v[j] = (bf16_t)p[j];
  *(bf16x8*)(packed + (size_t)c * 8) = v;
}

// ---------------- main persistent kernel: 64 WGs x 512 threads, 16 rows each ----------------
__global__ __launch_bounds__(512) void vrnn_main(
    const float* __restrict__ s, const float* __restrict__ noise,
    const bf16_t* __restrict__ packed, const float* __restrict__ fbias,
    const float* __restrict__ bp1, const float* __restrict__ bp2,
    const float* __restrict__ be2, const float* __restrict__ bd2,
    float* __restrict__ out) {
  const bf16x8* Wf = (const bf16x8*)packed;

  __shared__ __align__(16) bf16_t A_h[16 * 136];      // h (bf16), row stride 136
  __shared__ __align__(16) bf16_t A_s[2][16 * 72];    // s_t staged, stride 72, double-buffered
  __shared__ __align__(16) bf16_t A_z[16 * 72];
  __shared__ __align__(16) bf16_t A_e1[16 * 136];     // enc1 out; reused as dec1 out
  __shared__ __align__(16) bf16_t A_p1[16 * 136];
  __shared__ __align__(16) bf16_t zmu_s[1024], zsd_s[1024], pmu_s[1024], psd_s[1024];
  __shared__ __align__(16) bf16_t gact[16 * 512];     // activated gates i,f,g,o
  __shared__ float dec2o[1024];
  __shared__ float cst[2048];                          // c state fp32
  __shared__ float bsm[1216];                          // biases
  __shared__ float red[8];

  const int tid  = threadIdx.x;
  const int wv   = tid >> 6, ln = tid & 63;
  const int quad = ln >> 4, col = ln & 15;
  const int row0 = blockIdx.x * 16;
  const int pm_  = tid >> 5;           // pointwise row 0..15
  const int pj   = (tid & 31) * 2;     // pointwise col base
  const int nloc = wv * 16 + col;      // this wave's column for NT=8 layers

  // biases -> LDS: [0)be1f [128)bp1 [256)be2 [384)bp2 [512)bd1f [640)bd2 [704)bg
  for (int i = tid; i < 1216; i += 512) {
    float v;
    if      (i < 128)  v = fbias[i];
    else if (i < 256)  v = bp1[i - 128];
    else if (i < 384)  v = be2[i - 256];
    else if (i < 512)  v = bp2[i - 384];
    else if (i < 640)  v = fbias[128 + (i - 512)];
    else if (i < 704)  v = bd2[i - 640];
    else               v = fbias[256 + (i - 704)];
    bsm[i] = v;
  }
  for (int i = tid; i < 16 * 136; i += 512) A_h[i] = (bf16_t)0.0f;
  for (int i = tid; i < 2048; i += 512) cst[i] = 0.0f;
  { // stage s_0
    float2 v = *(const float2*)(s + (0 * BB + row0 + pm_) * 64 + pj);
    A_s[0][pm_ * 72 + pj]     = (bf16_t)v.x;
    A_s[0][pm_ * 72 + pj + 1] = (bf16_t)v.y;
  }

  // register-resident B-frags for the 3 gate layers (55% of MACs): 128 VGPRs/lane
  bf16x8 rb8[4][2], rb9[4][2], rb10[4][4];
  #pragma unroll
  for (int i = 0; i < 4; ++i) {
    int nt = wv + 8 * i;
    rb8[i][0] = Wf[cL8 + (nt * 2 + 0) * 64 + ln];
    rb8[i][1] = Wf[cL8 + (nt * 2 + 1) * 64 + ln];
    rb9[i][0] = Wf[cL9 + (nt * 2 + 0) * 64 + ln];
    rb9[i][1] = Wf[cL9 + (nt * 2 + 1) * 64 + ln];
    #pragma unroll
    for (int k = 0; k < 4; ++k) rb10[i][k] = Wf[cL10 + (nt * 4 + k) * 64 + ln];
  }

  float kl_acc = 0.0f, rc_acc = 0.0f;
  __syncthreads();

  for (int t = 0; t < TT; ++t) {
    const int sb = t & 1;
    // early prefetches (HBM streams)
    float2 nzv = *(const float2*)(noise + (t * BB + row0 + pm_) * 64 + pj);
    float2 svv = make_float2(0.f, 0.f);
    if (t + 1 < TT) svv = *(const float2*)(s + ((t + 1) * BB + row0 + pm_) * 64 + pj);
    float2 spv = make_float2(0.f, 0.f);
    if (t > 0) spv = *(const float2*)(s + ((t - 1) * BB + row0 + pm_) * 64 + pj);

    // ---- phase 1: everything that needs only (h, s_t) ----
    bf16x8 ah0 = *(const bf16x8*)&A_h[col * 136 + 0 + quad * 8];
    bf16x8 ah1 = *(const bf16x8*)&A_h[col * 136 + 32 + quad * 8];
    bf16x8 ah2 = *(const bf16x8*)&A_h[col * 136 + 64 + quad * 8];
    bf16x8 ah3 = *(const bf16x8*)&A_h[col * 136 + 96 + quad * 8];
    bf16x8 as0 = *(const bf16x8*)&A_s[sb][col * 72 + 0 + quad * 8];
    bf16x8 as1 = *(const bf16x8*)&A_s[sb][col * 72 + 32 + quad * 8];

    bf16x8 wE0a = Wf[cL0 + (wv * 2 + 0) * 64 + ln];
    bf16x8 wE0b = Wf[cL0 + (wv * 2 + 1) * 64 + ln];
    bf16x8 wE1[4], wP1[4], wD1[4];
    #pragma unroll
    for (int k = 0; k < 4; ++k) {
      wE1[k] = Wf[cL1 + (wv * 4 + k) * 64 + ln];
      wP1[k] = Wf[cL3 + (wv * 4 + k) * 64 + ln];
      wD1[k] = Wf[cL6 + (wv * 4 + k) * 64 + ln];
    }

    // gates partial (resident weights first -> overlaps streamed-load latency)
    f32x4 Cg[4];
    #pragma unroll
    for (int i = 0; i < 4; ++i) {
      int n = (wv + 8 * i) * 16 + col;
      float bv = bsm[704 + n];
      f32x4 cc = {bv, bv, bv, bv};
      cc = mfma16(as0, rb8[i][0], cc);
      cc = mfma16(as1, rb8[i][1], cc);
      cc = mfma16(ah0, rb10[i][0], cc);
      cc = mfma16(ah1, rb10[i][1], cc);
      cc = mfma16(ah2, rb10[i][2], cc);
      cc = mfma16(ah3, rb10[i][3], cc);
      Cg[i] = cc;
    }
    f32x4 Cd;  // dec1 h-part, held until phase 4
    {
      float bv = bsm[512 + nloc];
      f32x4 cc = {bv, bv, bv, bv};
      cc = mfma16(ah0, wD1[0], cc);
      cc = mfma16(ah1, wD1[1], cc);
      cc = mfma16(ah2, wD1[2], cc);
      cc = mfma16(ah3, wD1[3], cc);
      Cd = cc;
    }
    {  // enc1 = relu(s@A_es + h@We1b + b)
      float bv = bsm[nloc];
      f32x4 c = {bv, bv, bv, bv};
      c = mfma16(as0, wE0a, c);
      c = mfma16(as1, wE0b, c);
      c = mfma16(ah0, wE1[0], c);
      c = mfma16(ah1, wE1[1], c);
      c = mfma16(ah2, wE1[2], c);
      c = mfma16(ah3, wE1[3], c);
      #pragma unroll
      for (int r = 0; r < 4; ++r)
        A_e1[(quad * 4 + r) * 136 + nloc] = (bf16_t)fmaxf(c[r], 0.0f);
    }
    {  // pri1 = relu(h@Wp1 + bp1)
      float bv = bsm[128 + nloc];
      f32x4 c = {bv, bv, bv, bv};
      c = mfma16(ah0, wP1[0], c);
      c = mfma16(ah1, wP1[1], c);
      c = mfma16(ah2, wP1[2], c);
      c = mfma16(ah3, wP1[3], c);
      #pragma unroll
      for (int r = 0; r < 4; ++r)
        A_p1[(quad * 4 + r) * 136 + nloc] = (bf16_t)fmaxf(c[r], 0.0f);
    }
    if (t > 0) {  // recon loss for t-1 (dec2o stable since prev phase5)
      float d0 = dec2o[pm_ * 64 + pj] - spv.x;
      float d1 = dec2o[pm_ * 64 + pj + 1] - spv.y;
      rc_acc += 0.5f * (d0 * d0 + d1 * d1);
    }
    __syncthreads();  // B1

    // ---- phase 2: enc2, pri2 ----
    {
      bf16x8 ae0 = *(const bf16x8*)&A_e1[col * 136 + 0 + quad * 8];
      bf16x8 ae1 = *(const bf16x8*)&A_e1[col * 136 + 32 + quad * 8];
      bf16x8 ae2 = *(const bf16x8*)&A_e1[col * 136 + 64 + quad * 8];
      bf16x8 ae3 = *(const bf16x8*)&A_e1[col * 136 + 96 + quad * 8];
      bf16x8 ap0 = *(const bf16x8*)&A_p1[col * 136 + 0 + quad * 8];
      bf16x8 ap1 = *(const bf16x8*)&A_p1[col * 136 + 32 + quad * 8];
      bf16x8 ap2 = *(const bf16x8*)&A_p1[col * 136 + 64 + quad * 8];
      bf16x8 ap3 = *(const bf16x8*)&A_p1[col * 136 + 96 + quad * 8];
      bf16x8 w2[4], w4[4];
      #pragma unroll
      for (int k = 0; k < 4; ++k) {
        w2[k] = Wf[cL2 + (wv * 4 + k) * 64 + ln];
        w4[k] = Wf[cL4 + (wv * 4 + k) * 64 + ln];
      }
      float bvE = bsm[256 + nloc], bvP = bsm[384 + nloc];
      f32x4 ce = {bvE, bvE, bvE, bvE};
      f32x4 cp = {bvP, bvP, bvP, bvP};
      ce = mfma16(ae0, w2[0], ce); cp = mfma16(ap0, w4[0], cp);
      ce = mfma16(ae1, w2[1], ce); cp = mfma16(ap1, w4[1], cp);
      ce = mfma16(ae2, w2[2], ce); cp = mfma16(ap2, w4[2], cp);
      ce = mfma16(ae3, w2[3], ce); cp = mfma16(ap3, w4[3], cp);
      if (wv < 4) {  // mu halves (cols 0..63)
        #pragma unroll
        for (int r = 0; r < 4; ++r) {
          zmu_s[(quad * 4 + r) * 64 + nloc] = (bf16_t)ce[r];
          pmu_s[(quad * 4 + r) * 64 + nloc] = (bf16_t)cp[r];
        }
      } else {       // std halves: softplus
        int n2 = nloc - 64;
        #pragma unroll
        for (int r = 0; r < 4; ++r) {
          zsd_s[(quad * 4 + r) * 64 + n2] = (bf16_t)softplus_f(ce[r]);
          psd_s[(quad * 4 + r) * 64 + n2] = (bf16_t)softplus_f(cp[r]);
        }
      }
    }
    __syncthreads();  // B2

    // ---- phase 3: z = mu + std*noise ; KL accumulation ----
    #pragma unroll
    for (int u = 0; u < 2; ++u) {
      int e = pm_ * 64 + pj + u;
      float zm = (float)zmu_s[e], zs = (float)zsd_s[e];
      float pmv = (float)pmu_s[e], ps = (float)psd_s[e];
      float nz = u ? nzv.y : nzv.x;
      A_z[pm_ * 72 + pj + u] = (bf16_t)(zm + zs * nz);
      float dm = zm - pmv;
      float den = __expf(2.0f * ps) - 1.0f;
      kl_acc += 0.5f * (2.0f * __logf(ps + 0.01f) - 2.0f * __logf(zs + 0.01f)
                        + (zs * zs + dm * dm) / den);
    }
    __syncthreads();  // B3

    // ---- phase 4: finish gates (+z part) & activate; finish dec1; stage s_{t+1} ----
    {
      bf16x8 az0 = *(const bf16x8*)&A_z[col * 72 + 0 + quad * 8];
      bf16x8 az1 = *(const bf16x8*)&A_z[col * 72 + 32 + quad * 8];
      bf16x8 w5a = Wf[cL5 + (wv * 2 + 0) * 64 + ln];
      bf16x8 w5b = Wf[cL5 + (wv * 2 + 1) * 64 + ln];
      #pragma unroll
      for (int i = 0; i < 4; ++i) {
        Cg[i] = mfma16(az0, rb9[i][0], Cg[i]);
        Cg[i] = mfma16(az1, rb9[i][1], Cg[i]);
      }
      #pragma unroll
      for (int i = 0; i < 4; ++i) {
        int nt = wv + 8 * i;
        int n = nt * 16 + col;
        bool isg = ((nt >> 3) == 2);  // g gate -> tanh, others sigmoid
        #pragma unroll
        for (int r = 0; r < 4; ++r) {
          float v = Cg[i][r];
          float a = isg ? tanh_f(v) : sigm(v);
          gact[(quad * 4 + r) * 512 + n] = (bf16_t)a;
        }
      }
      Cd = mfma16(az0, w5a, Cd);
      Cd = mfma16(az1, w5b, Cd);
      #pragma unroll
      for (int r = 0; r < 4; ++r)
        A_e1[(quad * 4 + r) * 136 + nloc] = (bf16_t)fmaxf(Cd[r], 0.0f);  // dec1 out
      if (t + 1 < TT) {
        A_s[sb ^ 1][pm_ * 72 + pj]     = (bf16_t)svv.x;
        A_s[sb ^ 1][pm_ * 72 + pj + 1] = (bf16_t)svv.y;
      }
    }
    __syncthreads();  // B4

    // ---- phase 5: dec2; LSTM state update ----
    if (wv < 4) {
      bf16x8 ad0 = *(const bf16x8*)&A_e1[col * 136 + 0 + quad * 8];
      bf16x8 ad1 = *(const bf16x8*)&A_e1[col * 136 + 32 + quad * 8];
      bf16x8 ad2 = *(const bf16x8*)&A_e1[col * 136 + 64 + quad * 8];
      bf16x8 ad3 = *(const bf16x8*)&A_e1[col * 136 + 96 + quad * 8];
      bf16x8 w7[4];
      #pragma unroll
      for (int k = 0; k < 4; ++k) w7[k] = Wf[cL7 + (wv * 4 + k) * 64 + ln];
      float bv = bsm[640 + nloc];
      f32x4 c = {bv, bv, bv, bv};
      c = mfma16(ad0, w7[0], c);
      c = mfma16(ad1, w7[1], c);
      c = mfma16(ad2, w7[2], c);
      c = mfma16(ad3, w7[3], c);
      #pragma unroll
      for (int r = 0; r < 4; ++r)
        dec2o[(quad * 4 + r) * 64 + nloc] = c[r];
    }
    #pragma unroll
    for (int u = 0; u < 4; ++u) {
      int e = tid * 4 + u;
      int m = e >> 7, j = e & 127;
      float gi = (float)gact[m * 512 + j];
      float gf = (float)gact[m * 512 + 128 + j];
      float gg = (float)gact[m * 512 + 256 + j];
      float go = (float)gact[m * 512 + 384 + j];
      float cn = gf * cst[e] + gi * gg;
      cst[e] = cn;
      A_h[m * 136 + j] = (bf16_t)(go * tanh_f(cn));
    }
    __syncthreads();  // B5 (h,c,dec2o published for next step)
  }

  // final recon for t = TT-1
  {
    float2 sl = *(const float2*)(s + ((TT - 1) * BB + row0 + pm_) * 64 + pj);
    float d0 = dec2o[pm_ * 64 + pj] - sl.x;
    float d1 = dec2o[pm_ * 64 + pj + 1] - sl.y;
    rc_acc += 0.5f * (d0 * d0 + d1 * d1);
  }

  float tot = (kl_acc + rc_acc) * (1.0f / 1024.0f);  // mean over batch
  #pragma unroll
  for (int off = 32; off > 0; off >>= 1) tot += __shfl_down(tot, off);
  if (ln == 0) red[wv] = tot;
  __syncthreads();
  if (tid == 0) {
    float sum = 0.f;
    #pragma unroll
    for (int i = 0; i < 8; ++i) sum += red[i];
    atomicAdd(out, sum);
  }
}

extern "C" void kernel_launch(void* const* d_in, const int* in_sizes, int n_in,
                              void* d_out, int out_size, void* d_ws, size_t ws_size,
                              hipStream_t stream) {
  (void)in_sizes; (void)n_in; (void)out_size; (void)ws_size;
  const float* s   = (const float*)d_in[0];
  const float* nz  = (const float*)d_in[1];
  const float* Wps = (const float*)d_in[2];
  const float* bps = (const float*)d_in[3];
  const float* Wpz = (const float*)d_in[4];
  const float* bpz = (const float*)d_in[5];
  const float* Wp1 = (const float*)d_in[6];
  const float* bp1 = (const float*)d_in[7];
  const float* Wp2 = (const float*)d_in[8];
  const float* bp2 = (const float*)d_in[9];
  const float* We1 = (const float*)d_in[10];
  const float* be1 = (const float*)d_in[11];
  const float* We2 = (const float*)d_in[12];
  const float* be2 = (const float*)d_in[13];
  const float* Wih = (const float*)d_in[14];
  const float* bih = (const float*)d_in[15];
  const float* Whh = (const float*)d_in[16];
  const float* bhh = (const float*)d_in[17];
  const float* Wd1 = (const float*)d_in[18];
  const float* bd1 = (const float*)d_in[19];
  const float* Wd2 = (const float*)d_in[20];
  const float* bd2 = (const float*)d_in[21];

  bf16_t* packed = (bf16_t*)d_ws;
  float* fbias = (float*)((char*)d_ws + WS_FBIAS_OFF);
  float* fold  = (float*)((char*)d_ws + WS_FOLD_OFF);

  hipMemsetAsync(d_out, 0, sizeof(float), stream);
  vrnn_fold<<<(82688 + 255) / 256, 256, 0, stream>>>(We1, Wd1, Wih, Wps, Wpz, bps, bpz,
                                                     be1, bd1, bih, bhh, fold, fbias);
  vrnn_pack<<<(NCHUNK + 255) / 256, 256, 0, stream>>>(fold, We1, We2, Wp1, Wp2, Wd1, Wd2,
                                                      Whh, packed);
  vrnn_main<<<64, 512, 0, stream>>>(s, nz, packed, fbias, bp1, bp2, be2, bd2, (float*)d_out);
}